// Round 2
// baseline (112.804 us; speedup 1.0000x reference)
//
#include <hip/hip_runtime.h>
#include <stdint.h>

// Problem constants (from reference setup_inputs)
#define BB    8
#define NN    16384
#define KK    1024
#define KNN   16
#define QTR   (NN / 4)      // each of 4 waves per block owns a quarter of points
#define QGRP  (QTR / 4)     // float4-groups (4 pts) per quarter = 1024
#define PGRP  256           // pilot groups per quarter (= 1024 pts, as R9-R11)
#define HCAP  96            // survivor slots per (center, quarter); mean ~19
#define NGRP_TOT (BB * NN / 4)   // 32768 groups total (prep kernel)

typedef unsigned long long u64;
typedef float f32x2 __attribute__((ext_vector_type(2)));
typedef float f32x4 __attribute__((ext_vector_type(4)));

// ---- packed fp32 FMA (VOP3P): lo/hi slots are independent IEEE fma, ----
// ---- bit-identical to __fmaf_rn per slot (default op_sel_hi:[1,1,1]) ----
__device__ __forceinline__ f32x2 pk_fma(f32x2 a, f32x2 b, f32x2 c) {
    f32x2 d;
    asm("v_pk_fma_f32 %0, %1, %2, %3" : "=v"(d) : "v"(a), "v"(b), "v"(c));
    return d;
}

// Manual 64-bit shuffle-xor (two 32-bit shuffles).
__device__ __forceinline__ u64 shfl_xor_u64(u64 v, int mask) {
    int lo = (int)(uint32_t)v;
    int hi = (int)(uint32_t)(v >> 32);
    lo = __shfl_xor(lo, mask, 64);
    hi = __shfl_xor(hi, mask, 64);
    return ((u64)(uint32_t)hi << 32) | (u64)(uint32_t)lo;
}

// 64-bit shuffle from a dynamic source lane.
__device__ __forceinline__ u64 shfl_u64(u64 v, int src) {
    int lo = __shfl((int)(uint32_t)v, src, 64);
    int hi = __shfl((int)(uint32_t)(v >> 32), src, 64);
    return ((u64)(uint32_t)hi << 32) | (u64)(uint32_t)lo;
}

// Butterfly min over all 64 lanes; every lane ends with the wave minimum.
__device__ __forceinline__ u64 wave_min_u64(u64 v) {
#pragma unroll
    for (int off = 32; off > 0; off >>= 1) {
        u64 o = shfl_xor_u64(v, off);
        v = o < v ? o : v;
    }
    return v;
}

// Full 64-lane bitonic sort (ascending) of u64 keys carrying a 32-bit payload.
// Real keys are unique ((dist,idx) with unique idx); only padding (~0ull) can
// collide, and padding lanes have all-padding lists, so payload mixing among
// them is harmless. (Extraction scheme verified on-harness in R12, absmax=0.)
__device__ __forceinline__ void sort64_kv(u64& key, uint32_t& pay, int lane) {
#pragma unroll
    for (int k = 2; k <= 64; k <<= 1) {
#pragma unroll
        for (int j = k >> 1; j > 0; j >>= 1) {
            u64 okey = shfl_xor_u64(key, j);
            uint32_t opay = (uint32_t)__shfl_xor((int)pay, j, 64);
            bool tmin = ((lane & j) == 0) == ((lane & k) == 0);
            bool osm = okey < key;
            bool take = tmin ? osm : !osm;
            if (take) { key = okey; pay = opay; }
        }
    }
}

// Full 64-lane bitonic sort (ascending) of u64 keys, no payload.
__device__ __forceinline__ void sort64_k(u64& key, int lane) {
#pragma unroll
    for (int k = 2; k <= 64; k <<= 1) {
#pragma unroll
        for (int j = k >> 1; j > 0; j >>= 1) {
            u64 okey = shfl_xor_u64(key, j);
            bool tmin = ((lane & j) == 0) == ((lane & k) == 0);
            bool osm = okey < key;
            bool take = tmin ? osm : !osm;
            if (take) key = okey;
        }
    }
}

// EXACT reference d2 (final ranking + fallback): cross = sequential FMA chain
// (einsum -> dot_general -> BLAS microkernel semantics, verified R3);
// x_sq/c_sq plain non-FMA reduce, elementwise ops left-to-right.
__device__ __forceinline__ float point_d2(const float* xb, int i,
                                          float c0, float c1, float c2, float csq) {
#pragma clang fp contract(off)
    float x0 = xb[i * 3 + 0];
    float x1 = xb[i * 3 + 1];
    float x2 = xb[i * 3 + 2];
    float xsq = (x0 * x0 + x1 * x1) + x2 * x2;
    float cross = __fmaf_rn(x2, c2, __fmaf_rn(x1, c1, x0 * c0));
    float d2 = (xsq + csq) - 2.0f * cross;
    return d2 < 0.0f ? 0.0f : d2;   // jnp.maximum(d2, 0)
}

// Cold-path exact fallback (full-N bubble scan), only on cap overflow.
__device__ __attribute__((noinline)) int fallback_scan(const float* xb,
                                                       float c0, float c1, float c2,
                                                       float csq, int lane) {
    u64 list[KNN];
#pragma unroll
    for (int j = 0; j < KNN; ++j) list[j] = ~0ull;
    for (int i = lane; i < NN; i += 64) {
        float d2 = point_d2(xb, i, c0, c1, c2, csq);
        float dist = __fsqrt_rn(d2);
        u64 key = ((u64)__float_as_uint(dist) << 32) | (u64)(uint32_t)i;
        if (key < list[KNN - 1]) {
#pragma unroll
            for (int j = 0; j < KNN; ++j) {
                bool lt = key < list[j];
                u64 lo = lt ? key : list[j];
                u64 hi = lt ? list[j] : key;
                list[j] = lo;
                key = hi;
            }
        }
    }
    int res = 0;
    for (int it = 0; it < KNN; ++it) {
        u64 best = wave_min_u64(list[0]);
        if (it == lane) res = (int)(uint32_t)best;
        if (list[0] == best) {
#pragma unroll
            for (int j = 0; j < KNN - 1; ++j) list[j] = list[j + 1];
            list[KNN - 1] = ~0ull;
        }
    }
    return res;
}

// 16th-smallest FLOAT (true float order incl. negatives) of the 64 lane
// values, via full bitonic sort across lanes; lane 15 holds the answer.
__device__ __forceinline__ float sixteenth_smallest(float m, int lane) {
    uint32_t u = __float_as_uint(m);
    uint32_t s = (u & 0x80000000u) ? ~u : (u | 0x80000000u);  // sortable bits
    u64 v = ((u64)s << 32) | (unsigned)lane;                  // unique keys
#pragma unroll
    for (int k = 2; k <= 64; k <<= 1) {
#pragma unroll
        for (int j = k >> 1; j > 0; j >>= 1) {
            u64 o = shfl_xor_u64(v, j);
            bool up = (lane & k) == 0;          // k=64: ascending
            bool takeMin = ((lane & j) == 0) == up;
            u64 mn = v < o ? v : o;
            u64 mx = v < o ? o : v;
            v = takeMin ? mn : mx;
        }
    }
    uint32_t sb = (uint32_t)__shfl((int)(uint32_t)(v >> 32), 15, 64);
    uint32_t ub = (sb & 0x80000000u) ? (sb ^ 0x80000000u) : ~sb;
    return __uint_as_float(ub);
}

// Unpack a group of 4 AoS points (3 float4 = 48 B) + their exact xs.
__device__ __forceinline__ void load_group(const float4* x4, int g,
                                           float (&px)[4], float (&py)[4],
                                           float (&pz)[4], float (&xs)[4]) {
#pragma clang fp contract(off)
    float4 f0 = x4[g * 3 + 0];
    float4 f1 = x4[g * 3 + 1];
    float4 f2 = x4[g * 3 + 2];
    px[0] = f0.x; py[0] = f0.y; pz[0] = f0.z;
    px[1] = f0.w; py[1] = f1.x; pz[1] = f1.y;
    px[2] = f1.z; py[2] = f1.w; pz[2] = f2.x;
    px[3] = f2.y; py[3] = f2.z; pz[3] = f2.w;
#pragma unroll
    for (int k = 0; k < 4; ++k)
        xs[k] = (px[k] * px[k] + py[k] * py[k]) + pz[k] * pz[k];  // non-FMA, exact
}

// ---- R13 prep kernel: AoS xyz -> per-batch SoA {X, Y, Z, XS} in d_ws. ----
// xs uses the IDENTICAL non-FMA expression as load_group -> d' downstream is
// bit-identical to the R11 inline path (T/U filter argument transfers).
__global__ __launch_bounds__(256) void prep_kernel(const float* __restrict__ xyz,
                                                   float* __restrict__ soa) {
#pragma clang fp contract(off)
    int g = (int)blockIdx.x * 256 + (int)threadIdx.x;   // global group < 32768
    const float4* x4 = (const float4*)xyz;
    float px[4], py[4], pz[4], xs[4];
    load_group(x4, g, px, py, pz, xs);
    int b = g >> 12;             // 4096 groups per batch
    int gl = g & 4095;
    f32x4* out4 = (f32x4*)(soa + (size_t)b * NN * 4);
    out4[gl]          = f32x4{px[0], px[1], px[2], px[3]};
    out4[4096  + gl]  = f32x4{py[0], py[1], py[2], py[3]};
    out4[8192  + gl]  = f32x4{pz[0], pz[1], pz[2], pz[3]};
    out4[12288 + gl]  = f32x4{xs[0], xs[1], xs[2], xs[3]};
}

// R13 structure = R11 block shape (4 waves / 4 centers / 2048 blocks, which
// held 58% occupancy vs R12's 37%) + two VALU cuts:
//  (a) scan math in v_pk_fma_f32 pairs fed by SoA loads (prep kernel above):
//      48 scalar FMA + 20 xs ops per group -> 24 pk_fma, bit-identical d'.
//  (b) extraction by two bitonic sorts (R12-verified) instead of 16 serial
//      wave-mins: 96 -> 46 dependent cross-lane hops, ~376 fewer VALU.
// SOA=false fallback (ws too small) packs pairs from AoS loads instead.
template<bool SOA>
__global__ __launch_bounds__(256, 6) void knn_kernel(const float* __restrict__ xyz,
                                                     const float* __restrict__ centers,
                                                     const float* __restrict__ soa,
                                                     int* __restrict__ out) {
#pragma clang fp contract(off)
    const int q = (int)(threadIdx.x >> 6);    // wave in block = quarter = owned center
    const int lane = (int)(threadIdx.x & 63);
    const int cbase = (int)blockIdx.x * 4;    // global center id of center 0
    const int b = cbase >> 10;                // batch

    __shared__ float    s_min[4][256];        // [center][srcwave*64+lane] 4 KB
    __shared__ float    s_T[4];               // [center]
    __shared__ int      s_cnt[4][4];          // [center][quarter]
    __shared__ uint32_t s_idx[4][4][HCAP];    // [center][quarter][slot] 6 KB

    // folded center consts as pk splats: n = -2*c (exact)
    f32x2 nx[4], ny[4], nz[4];
#pragma unroll
    for (int c = 0; c < 4; ++c) {
        float a0 = -2.0f * centers[(cbase + c) * 3 + 0];
        float a1 = -2.0f * centers[(cbase + c) * 3 + 1];
        float a2 = -2.0f * centers[(cbase + c) * 3 + 2];
        nx[c] = f32x2{a0, a0};
        ny[c] = f32x2{a1, a1};
        nz[c] = f32x2{a2, a2};
    }

    const float* xb = xyz + (size_t)b * NN * 3;
    const float4* x4 = (const float4*)xb;     // batch base is 16B-aligned
    const f32x4* sb4 = (const f32x4*)(soa + (size_t)b * NN * 4);
    const int gbase = q * QGRP;               // first group of this quarter

    // Pair loader: xl/yl/zl/sl = points {0,1} of the group, xh/.. = {2,3}.
    auto load_pairs = [&](int g, f32x2& xl, f32x2& xh, f32x2& yl, f32x2& yh,
                          f32x2& zl, f32x2& zh, f32x2& sl, f32x2& sh) {
        if constexpr (SOA) {
            f32x4 X = sb4[g];
            f32x4 Y = sb4[4096 + g];
            f32x4 Z = sb4[8192 + g];
            f32x4 S = sb4[12288 + g];
            xl = __builtin_shufflevector(X, X, 0, 1);
            xh = __builtin_shufflevector(X, X, 2, 3);
            yl = __builtin_shufflevector(Y, Y, 0, 1);
            yh = __builtin_shufflevector(Y, Y, 2, 3);
            zl = __builtin_shufflevector(Z, Z, 0, 1);
            zh = __builtin_shufflevector(Z, Z, 2, 3);
            sl = __builtin_shufflevector(S, S, 0, 1);
            sh = __builtin_shufflevector(S, S, 2, 3);
        } else {
            float px[4], py[4], pz[4], xs[4];
            load_group(x4, g, px, py, pz, xs);
            xl = f32x2{px[0], px[1]}; xh = f32x2{px[2], px[3]};
            yl = f32x2{py[0], py[1]}; yh = f32x2{py[2], py[3]};
            zl = f32x2{pz[0], pz[1]}; zh = f32x2{pz[2], pz[3]};
            sl = f32x2{xs[0], xs[1]}; sh = f32x2{xs[2], xs[3]};
        }
    };

    // ---- Phase 1: pilot minima over first PGRP groups of this quarter ----
    float m[4];
#pragma unroll
    for (int c = 0; c < 4; ++c) m[c] = __builtin_inff();
#pragma unroll 2
    for (int s = 0; s < PGRP / 64; ++s) {     // 4 superiters
        int g = gbase + s * 64 + lane;
        f32x2 xl, xh, yl, yh, zl, zh, sl, sh;
        load_pairs(g, xl, xh, yl, yh, zl, zh, sl, sh);
#pragma unroll
        for (int c = 0; c < 4; ++c) {
            f32x2 dl = pk_fma(xl, nx[c], pk_fma(yl, ny[c], pk_fma(zl, nz[c], sl)));
            f32x2 dh = pk_fma(xh, nx[c], pk_fma(yh, ny[c], pk_fma(zh, nz[c], sh)));
            m[c] = fminf(m[c], fminf(fminf(dl.x, dl.y), fminf(dh.x, dh.y)));
        }
    }
#pragma unroll
    for (int c = 0; c < 4; ++c) s_min[c][threadIdx.x] = m[c];
    if (threadIdx.x < 16) s_cnt[threadIdx.x >> 2][threadIdx.x & 3] = 0;
    __syncthreads();
    {
        // wave q: per-lane min across the 4 source waves for center q, then
        // one bitonic. Each min-of-4 is still a single real point's d'.
        float v = fminf(fminf(s_min[q][lane], s_min[q][64 + lane]),
                        fminf(s_min[q][128 + lane], s_min[q][192 + lane]));
        float t = sixteenth_smallest(v, lane);
        if (lane == 0) s_T[q] = t;
    }
    __syncthreads();
    float U[4];
#pragma unroll
    for (int c = 0; c < 4; ++c) {
        float T = s_T[c];
        U[c] = T + fabsf(T) * 1e-5f + 5e-4f;  // verified slack (R5-R10)
    }

    // ---- Phase 2: filter scan; divergent atomic compaction into LDS ----
#pragma unroll 2
    for (int s = 0; s < QGRP / 64; ++s) {     // 16 superiters
        int g = gbase + s * 64 + lane;
        f32x2 xl, xh, yl, yh, zl, zh, sl, sh;
        load_pairs(g, xl, xh, yl, yh, zl, zh, sl, sh);
        int ibase = g * 4;                    // batch-local point index of pt 0
#pragma unroll
        for (int c = 0; c < 4; ++c) {
            f32x2 dl = pk_fma(xl, nx[c], pk_fma(yl, ny[c], pk_fma(zl, nz[c], sl)));
            f32x2 dh = pk_fma(xh, nx[c], pk_fma(yh, ny[c], pk_fma(zh, nz[c], sh)));
            if (dl.x <= U[c]) {
                int pos = atomicAdd(&s_cnt[c][q], 1);
                if (pos < HCAP) s_idx[c][q][pos] = (uint32_t)(ibase + 0);
            }
            if (dl.y <= U[c]) {
                int pos = atomicAdd(&s_cnt[c][q], 1);
                if (pos < HCAP) s_idx[c][q][pos] = (uint32_t)(ibase + 1);
            }
            if (dh.x <= U[c]) {
                int pos = atomicAdd(&s_cnt[c][q], 1);
                if (pos < HCAP) s_idx[c][q][pos] = (uint32_t)(ibase + 2);
            }
            if (dh.y <= U[c]) {
                int pos = atomicAdd(&s_cnt[c][q], 1);
                if (pos < HCAP) s_idx[c][q][pos] = (uint32_t)(ibase + 3);
            }
        }
    }
    __syncthreads();

    // ---- Phase 3: wave q reranks center q exactly (no idle waves) ----
    const int cc = cbase + q;
    const float c0 = centers[cc * 3 + 0];
    const float c1 = centers[cc * 3 + 1];
    const float c2 = centers[cc * 3 + 2];
    const float csq = (c0 * c0 + c1 * c1) + c2 * c2;  // exact non-FMA reduce
    const int k0 = s_cnt[q][0], k1 = s_cnt[q][1], k2 = s_cnt[q][2], k3 = s_cnt[q][3];
    const int p1o = k0, p2o = k0 + k1, p3o = k0 + k1 + k2;
    const int total = p3o + k3;
    const bool ok = (k0 <= HCAP) & (k1 <= HCAP) & (k2 <= HCAP) & (k3 <= HCAP) &
                    (total <= 4 * 64);

    uint32_t res;
    if (ok) {
        // Combined stream -> <= 4 keys/lane -> depth-4 list is exact.
        u64 l0 = ~0ull, l1 = ~0ull, l2 = ~0ull, l3 = ~0ull;
        for (int j = lane; j < total; j += 64) {
            int qq, off;
            if (j < p1o)      { qq = 0; off = j; }
            else if (j < p2o) { qq = 1; off = j - p1o; }
            else if (j < p3o) { qq = 2; off = j - p2o; }
            else              { qq = 3; off = j - p3o; }
            int idx = (int)s_idx[q][qq][off];
            float d2 = point_d2(xb, idx, c0, c1, c2, csq);
            u64 key = ((u64)__float_as_uint(__fsqrt_rn(d2)) << 32) | (u64)(uint32_t)idx;
            bool t;
            t = key < l0; { u64 lo = t ? key : l0, hi = t ? l0 : key; l0 = lo; key = hi; }
            t = key < l1; { u64 lo = t ? key : l1, hi = t ? l1 : key; l1 = lo; key = hi; }
            t = key < l2; { u64 lo = t ? key : l2, hi = t ? l2 : key; l2 = lo; key = hi; }
            t = key < l3; { u64 lo = t ? key : l3, hi = t ? l3 : key; l3 = lo; key = hi; }
        }
        // Selection (R12-verified): sort1 over per-lane minima (l0) with
        // source-lane payload. Global top-16 can only live in the 16 lanes
        // owning the 16 smallest l0s (lane lists are sorted); >=16 real keys
        // exist (16 pilot points with d' <= T <= U are stored when ok).
        u64 key = l0;
        uint32_t pay = (uint32_t)lane;
        sort64_kv(key, pay, lane);
        // Gather: lane i takes element (i&3) of the lane ranked (i>>2).
        int pos = lane >> 2, elem = lane & 3;
        int sid = __shfl((int)pay, pos, 64);
        u64 g0 = shfl_u64(l0, sid);
        u64 g1 = shfl_u64(l1, sid);
        u64 g2 = shfl_u64(l2, sid);
        u64 g3 = shfl_u64(l3, sid);
        u64 gk = (elem == 0) ? g0 : (elem == 1) ? g1 : (elem == 2) ? g2 : g3;
        // sort2: 64 candidates (superset of top-16) -> lanes 0..15 hold
        // ranks 0..15 in exact (dist,idx) order.
        sort64_k(gk, lane);
        res = (uint32_t)gk;
    } else {
        res = (uint32_t)fallback_scan(xb, c0, c1, c2, csq, lane);
    }

    // out[b][rank][c_in_batch]
    if (lane < KNN) {
        out[((size_t)b * KNN + lane) * KK + (cc & 1023)] = (int)res;
    }
}

extern "C" void kernel_launch(void* const* d_in, const int* in_sizes, int n_in,
                              void* d_out, int out_size, void* d_ws, size_t ws_size,
                              hipStream_t stream) {
    const float* xyz = (const float*)d_in[0];
    const float* centers = (const float*)d_in[1];
    int* out = (int*)d_out;

    const int nblocks = BB * KK / 4;   // 2048 blocks x 4 waves
    const size_t need = (size_t)BB * NN * 4 * sizeof(float);   // 2 MB SoA
    if (d_ws != nullptr && ws_size >= need) {
        hipLaunchKernelGGL(prep_kernel, dim3(NGRP_TOT / 256), dim3(256), 0, stream,
                           xyz, (float*)d_ws);
        hipLaunchKernelGGL((knn_kernel<true>), dim3(nblocks), dim3(256), 0, stream,
                           xyz, centers, (const float*)d_ws, out);
    } else {
        hipLaunchKernelGGL((knn_kernel<false>), dim3(nblocks), dim3(256), 0, stream,
                           xyz, centers, (const float*)nullptr, out);
    }
}

// Round 3
// 98.893 us; speedup vs baseline: 1.1407x; 1.1407x over previous
//
#include <hip/hip_runtime.h>
#include <stdint.h>

// Problem constants (from reference setup_inputs)
#define BB    8
#define NN    16384
#define KK    1024
#define KNN   16
#define QTR   (NN / 4)      // each of 4 waves per block owns a quarter of points
#define QGRP  (QTR / 4)     // float4-groups (4 pts) per quarter = 1024
#define PGRP  256           // pilot groups per quarter (= 1024 pts, as R9-R11)
#define HCAP  96            // survivor slots per (center, quarter); mean ~19

typedef unsigned long long u64;
typedef float f32x2 __attribute__((ext_vector_type(2)));

// ---- packed fp32 ops (VOP3P): lo/hi slots are independent IEEE ops, ----
// ---- bit-identical per slot to the scalar versions (op_sel_hi default) ----
__device__ __forceinline__ f32x2 pk_fma(f32x2 a, f32x2 b, f32x2 c) {
    f32x2 d;
    asm("v_pk_fma_f32 %0, %1, %2, %3" : "=v"(d) : "v"(a), "v"(b), "v"(c));
    return d;
}
__device__ __forceinline__ f32x2 pk_mul(f32x2 a, f32x2 b) {
    f32x2 d;
    asm("v_pk_mul_f32 %0, %1, %2" : "=v"(d) : "v"(a), "v"(b));
    return d;
}
__device__ __forceinline__ f32x2 pk_add(f32x2 a, f32x2 b) {
    f32x2 d;
    asm("v_pk_add_f32 %0, %1, %2" : "=v"(d) : "v"(a), "v"(b));
    return d;
}

// Manual 64-bit shuffle-xor (two 32-bit shuffles).
__device__ __forceinline__ u64 shfl_xor_u64(u64 v, int mask) {
    int lo = (int)(uint32_t)v;
    int hi = (int)(uint32_t)(v >> 32);
    lo = __shfl_xor(lo, mask, 64);
    hi = __shfl_xor(hi, mask, 64);
    return ((u64)(uint32_t)hi << 32) | (u64)(uint32_t)lo;
}

// 64-bit shuffle from a dynamic source lane.
__device__ __forceinline__ u64 shfl_u64(u64 v, int src) {
    int lo = __shfl((int)(uint32_t)v, src, 64);
    int hi = __shfl((int)(uint32_t)(v >> 32), src, 64);
    return ((u64)(uint32_t)hi << 32) | (u64)(uint32_t)lo;
}

// Butterfly min over all 64 lanes; every lane ends with the wave minimum.
__device__ __forceinline__ u64 wave_min_u64(u64 v) {
#pragma unroll
    for (int off = 32; off > 0; off >>= 1) {
        u64 o = shfl_xor_u64(v, off);
        v = o < v ? o : v;
    }
    return v;
}

// Full 64-lane bitonic sort (ascending) of u64 keys carrying a 32-bit payload.
// Real keys are unique ((dist,idx) with unique idx); only padding (~0ull) can
// collide, and padding lanes have all-padding lists, so payload mixing among
// them is harmless. (Extraction scheme harness-verified in R12+R13, absmax=0.)
__device__ __forceinline__ void sort64_kv(u64& key, uint32_t& pay, int lane) {
#pragma unroll
    for (int k = 2; k <= 64; k <<= 1) {
#pragma unroll
        for (int j = k >> 1; j > 0; j >>= 1) {
            u64 okey = shfl_xor_u64(key, j);
            uint32_t opay = (uint32_t)__shfl_xor((int)pay, j, 64);
            bool tmin = ((lane & j) == 0) == ((lane & k) == 0);
            bool osm = okey < key;
            bool take = tmin ? osm : !osm;
            if (take) { key = okey; pay = opay; }
        }
    }
}

// Full 64-lane bitonic sort (ascending) of u64 keys, no payload.
__device__ __forceinline__ void sort64_k(u64& key, int lane) {
#pragma unroll
    for (int k = 2; k <= 64; k <<= 1) {
#pragma unroll
        for (int j = k >> 1; j > 0; j >>= 1) {
            u64 okey = shfl_xor_u64(key, j);
            bool tmin = ((lane & j) == 0) == ((lane & k) == 0);
            bool osm = okey < key;
            bool take = tmin ? osm : !osm;
            if (take) key = okey;
        }
    }
}

// EXACT reference d2 (final ranking + fallback): cross = sequential FMA chain
// (einsum -> dot_general -> BLAS microkernel semantics, verified R3);
// x_sq/c_sq plain non-FMA reduce, elementwise ops left-to-right.
__device__ __forceinline__ float point_d2(const float* xb, int i,
                                          float c0, float c1, float c2, float csq) {
#pragma clang fp contract(off)
    float x0 = xb[i * 3 + 0];
    float x1 = xb[i * 3 + 1];
    float x2 = xb[i * 3 + 2];
    float xsq = (x0 * x0 + x1 * x1) + x2 * x2;
    float cross = __fmaf_rn(x2, c2, __fmaf_rn(x1, c1, x0 * c0));
    float d2 = (xsq + csq) - 2.0f * cross;
    return d2 < 0.0f ? 0.0f : d2;   // jnp.maximum(d2, 0)
}

// Cold-path exact fallback (full-N bubble scan), only on cap overflow.
__device__ __attribute__((noinline)) int fallback_scan(const float* xb,
                                                       float c0, float c1, float c2,
                                                       float csq, int lane) {
    u64 list[KNN];
#pragma unroll
    for (int j = 0; j < KNN; ++j) list[j] = ~0ull;
    for (int i = lane; i < NN; i += 64) {
        float d2 = point_d2(xb, i, c0, c1, c2, csq);
        float dist = __fsqrt_rn(d2);
        u64 key = ((u64)__float_as_uint(dist) << 32) | (u64)(uint32_t)i;
        if (key < list[KNN - 1]) {
#pragma unroll
            for (int j = 0; j < KNN; ++j) {
                bool lt = key < list[j];
                u64 lo = lt ? key : list[j];
                u64 hi = lt ? list[j] : key;
                list[j] = lo;
                key = hi;
            }
        }
    }
    int res = 0;
    for (int it = 0; it < KNN; ++it) {
        u64 best = wave_min_u64(list[0]);
        if (it == lane) res = (int)(uint32_t)best;
        if (list[0] == best) {
#pragma unroll
            for (int j = 0; j < KNN - 1; ++j) list[j] = list[j + 1];
            list[KNN - 1] = ~0ull;
        }
    }
    return res;
}

// 16th-smallest FLOAT (true float order incl. negatives) of the 64 lane
// values, via full bitonic sort across lanes; lane 15 holds the answer.
__device__ __forceinline__ float sixteenth_smallest(float m, int lane) {
    uint32_t u = __float_as_uint(m);
    uint32_t s = (u & 0x80000000u) ? ~u : (u | 0x80000000u);  // sortable bits
    u64 v = ((u64)s << 32) | (unsigned)lane;                  // unique keys
#pragma unroll
    for (int k = 2; k <= 64; k <<= 1) {
#pragma unroll
        for (int j = k >> 1; j > 0; j >>= 1) {
            u64 o = shfl_xor_u64(v, j);
            bool up = (lane & k) == 0;          // k=64: ascending
            bool takeMin = ((lane & j) == 0) == up;
            u64 mn = v < o ? v : o;
            u64 mx = v < o ? o : v;
            v = takeMin ? mn : mx;
        }
    }
    uint32_t sb = (uint32_t)__shfl((int)(uint32_t)(v >> 32), 15, 64);
    uint32_t ub = (sb & 0x80000000u) ? (sb ^ 0x80000000u) : ~sb;
    return __uint_as_float(ub);
}

// R14 loader: 3 contiguous dwordx4 AoS loads (identical memory pattern to the
// 53us R11 kernel -> FETCH stays ~6.5 MB), then in-register repack into six
// f32x2 position pairs (~12 v_mov) + PACKED exact xs:
// per slot sl/sh = (x*x + y*y) + z*z via pk_mul/pk_add -- the identical
// non-FMA operation sequence per element, bit-identical to the scalar path,
// so the R5-R10-verified T/U filter slack argument transfers unchanged.
__device__ __forceinline__ void load_pairs_aos(const float4* x4, int g,
                                               f32x2& xl, f32x2& xh,
                                               f32x2& yl, f32x2& yh,
                                               f32x2& zl, f32x2& zh,
                                               f32x2& sl, f32x2& sh) {
    float4 f0 = x4[g * 3 + 0];
    float4 f1 = x4[g * 3 + 1];
    float4 f2 = x4[g * 3 + 2];
    // points: p0=(f0.x,f0.y,f0.z) p1=(f0.w,f1.x,f1.y) p2=(f1.z,f1.w,f2.x) p3=(f2.y,f2.z,f2.w)
    xl = f32x2{f0.x, f0.w};  yl = f32x2{f0.y, f1.x};  zl = f32x2{f0.z, f1.y};
    xh = f32x2{f1.z, f2.y};  yh = f32x2{f1.w, f2.z};  zh = f32x2{f2.x, f2.w};
    sl = pk_add(pk_add(pk_mul(xl, xl), pk_mul(yl, yl)), pk_mul(zl, zl));
    sh = pk_add(pk_add(pk_mul(xh, xh), pk_mul(yh, yh)), pk_mul(zh, zh));
}

// R14 = R11 structure + memory pattern (4 waves / 4 centers / 2048 blocks =
// 8 blocks/CU one-shot residency) with the two R13-proven VALU cuts kept:
//  (a) scan math as v_pk_fma_f32 pairs (24 vs 48 FMA/group) + packed xs,
//      pairs packed in-register from the SAME AoS loads (no prep kernel,
//      no workspace, no SoA memory blowup);
//  (b) extraction by two bitonic sorts (R12/R13-verified) instead of 16
//      serial wave-mins (96 -> 46 dependent cross-lane hops).
__global__ __launch_bounds__(256, 8) void knn_kernel(const float* __restrict__ xyz,
                                                     const float* __restrict__ centers,
                                                     int* __restrict__ out) {
#pragma clang fp contract(off)
    const int q = (int)(threadIdx.x >> 6);    // wave in block = quarter = owned center
    const int lane = (int)(threadIdx.x & 63);
    const int cbase = (int)blockIdx.x * 4;    // global center id of center 0
    const int b = cbase >> 10;                // batch

    __shared__ float    s_min[4][256];        // [center][srcwave*64+lane] 4 KB
    __shared__ float    s_T[4];               // [center]
    __shared__ int      s_cnt[4][4];          // [center][quarter]
    __shared__ uint32_t s_idx[4][4][HCAP];    // [center][quarter][slot] 6 KB

    // folded center consts as pk splats: n = -2*c (exact)
    f32x2 nx[4], ny[4], nz[4];
#pragma unroll
    for (int c = 0; c < 4; ++c) {
        float a0 = -2.0f * centers[(cbase + c) * 3 + 0];
        float a1 = -2.0f * centers[(cbase + c) * 3 + 1];
        float a2 = -2.0f * centers[(cbase + c) * 3 + 2];
        nx[c] = f32x2{a0, a0};
        ny[c] = f32x2{a1, a1};
        nz[c] = f32x2{a2, a2};
    }

    const float* xb = xyz + (size_t)b * NN * 3;
    const float4* x4 = (const float4*)xb;     // batch base is 16B-aligned
    const int gbase = q * QGRP;               // first group of this quarter

    // ---- Phase 1: pilot minima over first PGRP groups of this quarter ----
    float m[4];
#pragma unroll
    for (int c = 0; c < 4; ++c) m[c] = __builtin_inff();
#pragma unroll 2
    for (int s = 0; s < PGRP / 64; ++s) {     // 4 superiters
        int g = gbase + s * 64 + lane;
        f32x2 xl, xh, yl, yh, zl, zh, sl, sh;
        load_pairs_aos(x4, g, xl, xh, yl, yh, zl, zh, sl, sh);
#pragma unroll
        for (int c = 0; c < 4; ++c) {
            f32x2 dl = pk_fma(xl, nx[c], pk_fma(yl, ny[c], pk_fma(zl, nz[c], sl)));
            f32x2 dh = pk_fma(xh, nx[c], pk_fma(yh, ny[c], pk_fma(zh, nz[c], sh)));
            m[c] = fminf(m[c], fminf(fminf(dl.x, dl.y), fminf(dh.x, dh.y)));
        }
    }
#pragma unroll
    for (int c = 0; c < 4; ++c) s_min[c][threadIdx.x] = m[c];
    if (threadIdx.x < 16) s_cnt[threadIdx.x >> 2][threadIdx.x & 3] = 0;
    __syncthreads();
    {
        // wave q: per-lane min across the 4 source waves for center q, then
        // one bitonic. Each min-of-4 is still a single real point's d'.
        float v = fminf(fminf(s_min[q][lane], s_min[q][64 + lane]),
                        fminf(s_min[q][128 + lane], s_min[q][192 + lane]));
        float t = sixteenth_smallest(v, lane);
        if (lane == 0) s_T[q] = t;
    }
    __syncthreads();
    float U[4];
#pragma unroll
    for (int c = 0; c < 4; ++c) {
        float T = s_T[c];
        U[c] = T + fabsf(T) * 1e-5f + 5e-4f;  // verified slack (R5-R10)
    }

    // ---- Phase 2: filter scan; divergent atomic compaction into LDS ----
#pragma unroll 2
    for (int s = 0; s < QGRP / 64; ++s) {     // 16 superiters
        int g = gbase + s * 64 + lane;
        f32x2 xl, xh, yl, yh, zl, zh, sl, sh;
        load_pairs_aos(x4, g, xl, xh, yl, yh, zl, zh, sl, sh);
        int ibase = g * 4;                    // batch-local point index of pt 0
#pragma unroll
        for (int c = 0; c < 4; ++c) {
            f32x2 dl = pk_fma(xl, nx[c], pk_fma(yl, ny[c], pk_fma(zl, nz[c], sl)));
            f32x2 dh = pk_fma(xh, nx[c], pk_fma(yh, ny[c], pk_fma(zh, nz[c], sh)));
            if (dl.x <= U[c]) {
                int pos = atomicAdd(&s_cnt[c][q], 1);
                if (pos < HCAP) s_idx[c][q][pos] = (uint32_t)(ibase + 0);
            }
            if (dl.y <= U[c]) {
                int pos = atomicAdd(&s_cnt[c][q], 1);
                if (pos < HCAP) s_idx[c][q][pos] = (uint32_t)(ibase + 1);
            }
            if (dh.x <= U[c]) {
                int pos = atomicAdd(&s_cnt[c][q], 1);
                if (pos < HCAP) s_idx[c][q][pos] = (uint32_t)(ibase + 2);
            }
            if (dh.y <= U[c]) {
                int pos = atomicAdd(&s_cnt[c][q], 1);
                if (pos < HCAP) s_idx[c][q][pos] = (uint32_t)(ibase + 3);
            }
        }
    }
    __syncthreads();

    // ---- Phase 3: wave q reranks center q exactly (no idle waves) ----
    const int cc = cbase + q;
    const float c0 = centers[cc * 3 + 0];
    const float c1 = centers[cc * 3 + 1];
    const float c2 = centers[cc * 3 + 2];
    const float csq = (c0 * c0 + c1 * c1) + c2 * c2;  // exact non-FMA reduce
    const int k0 = s_cnt[q][0], k1 = s_cnt[q][1], k2 = s_cnt[q][2], k3 = s_cnt[q][3];
    const int p1o = k0, p2o = k0 + k1, p3o = k0 + k1 + k2;
    const int total = p3o + k3;
    const bool ok = (k0 <= HCAP) & (k1 <= HCAP) & (k2 <= HCAP) & (k3 <= HCAP) &
                    (total <= 4 * 64);

    uint32_t res;
    if (ok) {
        // Combined stream -> <= 4 keys/lane -> depth-4 list is exact.
        u64 l0 = ~0ull, l1 = ~0ull, l2 = ~0ull, l3 = ~0ull;
        for (int j = lane; j < total; j += 64) {
            int qq, off;
            if (j < p1o)      { qq = 0; off = j; }
            else if (j < p2o) { qq = 1; off = j - p1o; }
            else if (j < p3o) { qq = 2; off = j - p2o; }
            else              { qq = 3; off = j - p3o; }
            int idx = (int)s_idx[q][qq][off];
            float d2 = point_d2(xb, idx, c0, c1, c2, csq);
            u64 key = ((u64)__float_as_uint(__fsqrt_rn(d2)) << 32) | (u64)(uint32_t)idx;
            bool t;
            t = key < l0; { u64 lo = t ? key : l0, hi = t ? l0 : key; l0 = lo; key = hi; }
            t = key < l1; { u64 lo = t ? key : l1, hi = t ? l1 : key; l1 = lo; key = hi; }
            t = key < l2; { u64 lo = t ? key : l2, hi = t ? l2 : key; l2 = lo; key = hi; }
            t = key < l3; { u64 lo = t ? key : l3, hi = t ? l3 : key; l3 = lo; key = hi; }
        }
        // Selection (R12/R13-verified): sort1 over per-lane minima (l0) with
        // source-lane payload. Global top-16 can only live in the 16 lanes
        // owning the 16 smallest l0s (lane lists are sorted); >=16 real keys
        // exist (16 pilot points with d' <= T <= U are stored when ok).
        u64 key = l0;
        uint32_t pay = (uint32_t)lane;
        sort64_kv(key, pay, lane);
        // Gather: lane i takes element (i&3) of the lane ranked (i>>2).
        int pos = lane >> 2, elem = lane & 3;
        int sid = __shfl((int)pay, pos, 64);
        u64 g0 = shfl_u64(l0, sid);
        u64 g1 = shfl_u64(l1, sid);
        u64 g2 = shfl_u64(l2, sid);
        u64 g3 = shfl_u64(l3, sid);
        u64 gk = (elem == 0) ? g0 : (elem == 1) ? g1 : (elem == 2) ? g2 : g3;
        // sort2: 64 candidates (superset of top-16) -> lanes 0..15 hold
        // ranks 0..15 in exact (dist,idx) order.
        sort64_k(gk, lane);
        res = (uint32_t)gk;
    } else {
        res = (uint32_t)fallback_scan(xb, c0, c1, c2, csq, lane);
    }

    // out[b][rank][c_in_batch]
    if (lane < KNN) {
        out[((size_t)b * KNN + lane) * KK + (cc & 1023)] = (int)res;
    }
}

extern "C" void kernel_launch(void* const* d_in, const int* in_sizes, int n_in,
                              void* d_out, int out_size, void* d_ws, size_t ws_size,
                              hipStream_t stream) {
    const float* xyz = (const float*)d_in[0];
    const float* centers = (const float*)d_in[1];
    int* out = (int*)d_out;
    (void)d_ws; (void)ws_size;

    const int nblocks = BB * KK / 4;   // 2048 blocks x 4 waves = 8 blocks/CU, one shot
    hipLaunchKernelGGL(knn_kernel, dim3(nblocks), dim3(256), 0, stream,
                       xyz, centers, out);
}

// Round 4
// 95.792 us; speedup vs baseline: 1.1776x; 1.0324x over previous
//
#include <hip/hip_runtime.h>
#include <stdint.h>

// Problem constants (from reference setup_inputs)
#define BB    8
#define NN    16384
#define KK    1024
#define KNN   16
#define QTR   (NN / 4)      // each of 4 waves per block owns a quarter of points
#define QGRP  (QTR / 4)     // 4-pt load-groups per quarter = 1024
#define NG16  (NN / 16)     // 16-pt groups per batch = 1024 (filter granularity)
#define GCAP  48            // admitted 16-pt groups per center (expected ~20)
#define SCAP  192           // survivor points per center (expected ~20; <=256 exact bound)

typedef unsigned long long u64;
typedef float f32x2 __attribute__((ext_vector_type(2)));

// ---- packed fp32 ops (VOP3P): lo/hi slots are independent IEEE ops, ----
// ---- bit-identical per slot to the scalar versions (op_sel_hi default) ----
__device__ __forceinline__ f32x2 pk_fma(f32x2 a, f32x2 b, f32x2 c) {
    f32x2 d;
    asm("v_pk_fma_f32 %0, %1, %2, %3" : "=v"(d) : "v"(a), "v"(b), "v"(c));
    return d;
}
__device__ __forceinline__ f32x2 pk_mul(f32x2 a, f32x2 b) {
    f32x2 d;
    asm("v_pk_mul_f32 %0, %1, %2" : "=v"(d) : "v"(a), "v"(b));
    return d;
}
__device__ __forceinline__ f32x2 pk_add(f32x2 a, f32x2 b) {
    f32x2 d;
    asm("v_pk_add_f32 %0, %1, %2" : "=v"(d) : "v"(a), "v"(b));
    return d;
}

// Manual 64-bit shuffle-xor (two 32-bit shuffles).
__device__ __forceinline__ u64 shfl_xor_u64(u64 v, int mask) {
    int lo = (int)(uint32_t)v;
    int hi = (int)(uint32_t)(v >> 32);
    lo = __shfl_xor(lo, mask, 64);
    hi = __shfl_xor(hi, mask, 64);
    return ((u64)(uint32_t)hi << 32) | (u64)(uint32_t)lo;
}

// 64-bit shuffle from a dynamic source lane.
__device__ __forceinline__ u64 shfl_u64(u64 v, int src) {
    int lo = __shfl((int)(uint32_t)v, src, 64);
    int hi = __shfl((int)(uint32_t)(v >> 32), src, 64);
    return ((u64)(uint32_t)hi << 32) | (u64)(uint32_t)lo;
}

// Butterfly min over all 64 lanes; every lane ends with the wave minimum.
__device__ __forceinline__ u64 wave_min_u64(u64 v) {
#pragma unroll
    for (int off = 32; off > 0; off >>= 1) {
        u64 o = shfl_xor_u64(v, off);
        v = o < v ? o : v;
    }
    return v;
}

// Full 64-lane bitonic sort (ascending) of u64 keys carrying a 32-bit payload.
// Real keys are unique ((dist,idx) with unique idx); only padding (~0ull) can
// collide, and padding lanes have all-padding lists, so payload mixing among
// them is harmless. (Extraction scheme harness-verified R12-R14, absmax=0.)
__device__ __forceinline__ void sort64_kv(u64& key, uint32_t& pay, int lane) {
#pragma unroll
    for (int k = 2; k <= 64; k <<= 1) {
#pragma unroll
        for (int j = k >> 1; j > 0; j >>= 1) {
            u64 okey = shfl_xor_u64(key, j);
            uint32_t opay = (uint32_t)__shfl_xor((int)pay, j, 64);
            bool tmin = ((lane & j) == 0) == ((lane & k) == 0);
            bool osm = okey < key;
            bool take = tmin ? osm : !osm;
            if (take) { key = okey; pay = opay; }
        }
    }
}

// Full 64-lane bitonic sort (ascending) of u64 keys, no payload.
__device__ __forceinline__ void sort64_k(u64& key, int lane) {
#pragma unroll
    for (int k = 2; k <= 64; k <<= 1) {
#pragma unroll
        for (int j = k >> 1; j > 0; j >>= 1) {
            u64 okey = shfl_xor_u64(key, j);
            bool tmin = ((lane & j) == 0) == ((lane & k) == 0);
            bool osm = okey < key;
            bool take = tmin ? osm : !osm;
            if (take) key = okey;
        }
    }
}

// EXACT reference d2 (final ranking + fallback): cross = sequential FMA chain
// (einsum -> dot_general -> BLAS microkernel semantics, verified R3);
// x_sq/c_sq plain non-FMA reduce, elementwise ops left-to-right.
__device__ __forceinline__ float point_d2(const float* xb, int i,
                                          float c0, float c1, float c2, float csq) {
#pragma clang fp contract(off)
    float x0 = xb[i * 3 + 0];
    float x1 = xb[i * 3 + 1];
    float x2 = xb[i * 3 + 2];
    float xsq = (x0 * x0 + x1 * x1) + x2 * x2;
    float cross = __fmaf_rn(x2, c2, __fmaf_rn(x1, c1, x0 * c0));
    float d2 = (xsq + csq) - 2.0f * cross;
    return d2 < 0.0f ? 0.0f : d2;   // jnp.maximum(d2, 0)
}

// Cold-path exact fallback (full-N bubble scan), only on cap overflow.
__device__ __attribute__((noinline)) int fallback_scan(const float* xb,
                                                       float c0, float c1, float c2,
                                                       float csq, int lane) {
    u64 list[KNN];
#pragma unroll
    for (int j = 0; j < KNN; ++j) list[j] = ~0ull;
    for (int i = lane; i < NN; i += 64) {
        float d2 = point_d2(xb, i, c0, c1, c2, csq);
        float dist = __fsqrt_rn(d2);
        u64 key = ((u64)__float_as_uint(dist) << 32) | (u64)(uint32_t)i;
        if (key < list[KNN - 1]) {
#pragma unroll
            for (int j = 0; j < KNN; ++j) {
                bool lt = key < list[j];
                u64 lo = lt ? key : list[j];
                u64 hi = lt ? list[j] : key;
                list[j] = lo;
                key = hi;
            }
        }
    }
    int res = 0;
    for (int it = 0; it < KNN; ++it) {
        u64 best = wave_min_u64(list[0]);
        if (it == lane) res = (int)(uint32_t)best;
        if (list[0] == best) {
#pragma unroll
            for (int j = 0; j < KNN - 1; ++j) list[j] = list[j + 1];
            list[KNN - 1] = ~0ull;
        }
    }
    return res;
}

// 16th-smallest FLOAT (true float order incl. negatives) of the 64 lane
// values, via full bitonic sort across lanes; all lanes get the answer.
__device__ __forceinline__ float sixteenth_smallest(float m, int lane) {
    uint32_t u = __float_as_uint(m);
    uint32_t s = (u & 0x80000000u) ? ~u : (u | 0x80000000u);  // sortable bits
    u64 v = ((u64)s << 32) | (unsigned)lane;                  // unique keys
#pragma unroll
    for (int k = 2; k <= 64; k <<= 1) {
#pragma unroll
        for (int j = k >> 1; j > 0; j >>= 1) {
            u64 o = shfl_xor_u64(v, j);
            bool up = (lane & k) == 0;          // k=64: ascending
            bool takeMin = ((lane & j) == 0) == up;
            u64 mn = v < o ? v : o;
            u64 mx = v < o ? o : v;
            v = takeMin ? mn : mx;
        }
    }
    uint32_t sb = (uint32_t)__shfl((int)(uint32_t)(v >> 32), 15, 64);
    uint32_t ub = (sb & 0x80000000u) ? (sb ^ 0x80000000u) : ~sb;
    return __uint_as_float(ub);
}

// AoS loader (R14-verified): 3 contiguous dwordx4 loads, in-register repack to
// six f32x2 pairs + PACKED exact xs (per slot (x*x + y*y) + z*z via
// pk_mul/pk_add -- bit-identical to the scalar non-FMA expression).
__device__ __forceinline__ void load_pairs_aos(const float4* x4, int g,
                                               f32x2& xl, f32x2& xh,
                                               f32x2& yl, f32x2& yh,
                                               f32x2& zl, f32x2& zh,
                                               f32x2& sl, f32x2& sh) {
    float4 f0 = x4[g * 3 + 0];
    float4 f1 = x4[g * 3 + 1];
    float4 f2 = x4[g * 3 + 2];
    // p0=(f0.x,f0.y,f0.z) p1=(f0.w,f1.x,f1.y) p2=(f1.z,f1.w,f2.x) p3=(f2.y,f2.z,f2.w)
    xl = f32x2{f0.x, f0.w};  yl = f32x2{f0.y, f1.x};  zl = f32x2{f0.z, f1.y};
    xh = f32x2{f1.z, f2.y};  yh = f32x2{f1.w, f2.z};  zh = f32x2{f2.x, f2.w};
    sl = pk_add(pk_add(pk_mul(xl, xl), pk_mul(yl, yl)), pk_mul(zl, zl));
    sh = pk_add(pk_add(pk_mul(xh, xh), pk_mul(yh, yh)), pk_mul(zh, zh));
}

// R15 structure (single-pass group-min filter):
//  Phase A: ONE full predicate-free scan. Per center, per 16-pt group, store
//    min d' (pk chain, bit-identical to R14 filter math) into LDS gmin
//    (4 centers x 1024 groups x 4B = 16 KB). No pilot, no atomics, no
//    per-point branches in the hot loop.
//  Threshold (wave q = center q): L16 = 16th-smallest of the 64 lane-mins
//    over gmin[q][*]. Any 16 distinct entries' max >= global 16th group-min
//    >= true 16th-smallest point d' (16 groups with min <= G16 contain >=16
//    points <= G16), so U = L16 + |L16|*1e-5 + 5e-4 (R5-R10-verified slack,
//    same pk metric) conservatively covers the reference top-16.
//  Admit: groups with gmin <= U (exactly the groups containing survivors,
//    ~20/center since the "sample" is now the full population).
//  Retest: recompute the IDENTICAL pk d' for admitted groups' 16 points,
//    append survivor indices (pk d' <= U). Contains all ref-top-16.
//  Rerank: R12-verified flat exact rerank (<=4 keys/lane, two bitonic sorts).
//  Fallback: cap overflow -> exact full scan (unchanged).
__global__ __launch_bounds__(256, 8) void knn_kernel(const float* __restrict__ xyz,
                                                     const float* __restrict__ centers,
                                                     int* __restrict__ out) {
#pragma clang fp contract(off)
    const int q = (int)(threadIdx.x >> 6);    // wave in block = quarter = owned center
    const int lane = (int)(threadIdx.x & 63);
    const int cbase = (int)blockIdx.x * 4;    // global center id of center 0
    const int b = cbase >> 10;                // batch

    __shared__ float    s_gmin[4][NG16];      // [center][16-pt group] 16 KB
    __shared__ uint32_t s_glist[4][GCAP];     // admitted group ids, 768 B
    __shared__ uint32_t s_idx[4][SCAP];       // survivor point ids, 3 KB
    __shared__ int      s_gcnt[4];
    __shared__ int      s_cnt[4];

    // folded center consts as pk splats: n = -2*c (exact)
    f32x2 nx[4], ny[4], nz[4];
#pragma unroll
    for (int c = 0; c < 4; ++c) {
        float a0 = -2.0f * centers[(cbase + c) * 3 + 0];
        float a1 = -2.0f * centers[(cbase + c) * 3 + 1];
        float a2 = -2.0f * centers[(cbase + c) * 3 + 2];
        nx[c] = f32x2{a0, a0};
        ny[c] = f32x2{a1, a1};
        nz[c] = f32x2{a2, a2};
    }

    const float* xb = xyz + (size_t)b * NN * 3;
    const float4* x4 = (const float4*)xb;     // batch base is 16B-aligned
    const int gbase = q * QGRP;               // first load-group of this quarter

    if (threadIdx.x < 4) { s_gcnt[threadIdx.x] = 0; s_cnt[threadIdx.x] = 0; }

    // ---- Phase A: full scan, per-center 16-pt group minima -> LDS ----
#pragma unroll 2
    for (int s = 0; s < QGRP / 64; ++s) {     // 16 superiters
        int g = gbase + s * 64 + lane;
        f32x2 xl, xh, yl, yh, zl, zh, sl, sh;
        load_pairs_aos(x4, g, xl, xh, yl, yh, zl, zh, sl, sh);
        float gm[4];
#pragma unroll
        for (int c = 0; c < 4; ++c) {
            f32x2 dl = pk_fma(xl, nx[c], pk_fma(yl, ny[c], pk_fma(zl, nz[c], sl)));
            f32x2 dh = pk_fma(xh, nx[c], pk_fma(yh, ny[c], pk_fma(zh, nz[c], sh)));
            float v = fminf(fminf(dl.x, dl.y), fminf(dh.x, dh.y));
            // 4-lane cluster (consecutive g) -> 16-pt group min
            v = fminf(v, __shfl_xor(v, 1, 64));
            v = fminf(v, __shfl_xor(v, 2, 64));
            gm[c] = v;
        }
        if ((lane & 3) == 0) {
            int gi = g >> 2;                  // batch 16-pt group id
#pragma unroll
            for (int c = 0; c < 4; ++c) s_gmin[c][gi] = gm[c];
        }
    }
    __syncthreads();

    // ---- Threshold + admit (wave q handles center q) ----
    float lm = __builtin_inff();
#pragma unroll
    for (int it = 0; it < NG16 / 64; ++it)
        lm = fminf(lm, s_gmin[q][it * 64 + lane]);
    float t = sixteenth_smallest(lm, lane);   // >= 16th group-min >= true T
    const float Uq = t + fabsf(t) * 1e-5f + 5e-4f;   // verified slack (R5-R10)

#pragma unroll
    for (int it = 0; it < NG16 / 64; ++it) {
        int gi = it * 64 + lane;
        if (s_gmin[q][gi] <= Uq) {
            int pos = atomicAdd(&s_gcnt[q], 1);
            if (pos < GCAP) s_glist[q][pos] = (uint32_t)gi;
        }
    }
    __syncthreads();

    const int ng = s_gcnt[q];
    bool ok = (ng <= GCAP);

    // ---- Retest: identical pk d' on admitted groups, gather survivors ----
    if (ok) {
        for (int j = lane; j < ng * 4; j += 64) {
            int lg = (int)s_glist[q][j >> 2] * 4 + (j & 3);   // load-group id
            f32x2 xl, xh, yl, yh, zl, zh, sl, sh;
            load_pairs_aos(x4, lg, xl, xh, yl, yh, zl, zh, sl, sh);
            f32x2 dl = pk_fma(xl, nx[q], pk_fma(yl, ny[q], pk_fma(zl, nz[q], sl)));
            f32x2 dh = pk_fma(xh, nx[q], pk_fma(yh, ny[q], pk_fma(zh, nz[q], sh)));
            int ibase = lg * 4;
            if (dl.x <= Uq) {
                int pos = atomicAdd(&s_cnt[q], 1);
                if (pos < SCAP) s_idx[q][pos] = (uint32_t)(ibase + 0);
            }
            if (dl.y <= Uq) {
                int pos = atomicAdd(&s_cnt[q], 1);
                if (pos < SCAP) s_idx[q][pos] = (uint32_t)(ibase + 1);
            }
            if (dh.x <= Uq) {
                int pos = atomicAdd(&s_cnt[q], 1);
                if (pos < SCAP) s_idx[q][pos] = (uint32_t)(ibase + 2);
            }
            if (dh.y <= Uq) {
                int pos = atomicAdd(&s_cnt[q], 1);
                if (pos < SCAP) s_idx[q][pos] = (uint32_t)(ibase + 3);
            }
        }
    }

    // ---- Rerank center q exactly ----
    const int cc = cbase + q;
    const float c0 = centers[cc * 3 + 0];
    const float c1 = centers[cc * 3 + 1];
    const float c2 = centers[cc * 3 + 2];
    const float csq = (c0 * c0 + c1 * c1) + c2 * c2;  // exact non-FMA reduce
    const int total = s_cnt[q];
    ok = ok && (total <= SCAP);               // SCAP <= 256 = depth-4 exact bound

    uint32_t res;
    if (ok) {
        // <= 3 keys/lane round-robin -> depth-4 list holds ALL of a lane's
        // keys -> union is the full survivor set (exact).
        u64 l0 = ~0ull, l1 = ~0ull, l2 = ~0ull, l3 = ~0ull;
        for (int j = lane; j < total; j += 64) {
            int idx = (int)s_idx[q][j];
            float d2 = point_d2(xb, idx, c0, c1, c2, csq);
            u64 key = ((u64)__float_as_uint(__fsqrt_rn(d2)) << 32) | (u64)(uint32_t)idx;
            bool tt;
            tt = key < l0; { u64 lo = tt ? key : l0, hi = tt ? l0 : key; l0 = lo; key = hi; }
            tt = key < l1; { u64 lo = tt ? key : l1, hi = tt ? l1 : key; l1 = lo; key = hi; }
            tt = key < l2; { u64 lo = tt ? key : l2, hi = tt ? l2 : key; l2 = lo; key = hi; }
            tt = key < l3; { u64 lo = tt ? key : l3, hi = tt ? l3 : key; l3 = lo; key = hi; }
        }
        // Selection (R12-R14-verified): top-16 lie in the 16 lanes with the
        // 16 smallest l0s (>=16 real keys exist: survivors contain the true
        // top-16, and they span >=4 groups -> total >= 16).
        u64 key = l0;
        uint32_t pay = (uint32_t)lane;
        sort64_kv(key, pay, lane);
        int pos = lane >> 2, elem = lane & 3;
        int sid = __shfl((int)pay, pos, 64);
        u64 g0 = shfl_u64(l0, sid);
        u64 g1 = shfl_u64(l1, sid);
        u64 g2 = shfl_u64(l2, sid);
        u64 g3 = shfl_u64(l3, sid);
        u64 gk = (elem == 0) ? g0 : (elem == 1) ? g1 : (elem == 2) ? g2 : g3;
        sort64_k(gk, lane);
        res = (uint32_t)gk;
    } else {
        res = (uint32_t)fallback_scan(xb, c0, c1, c2, csq, lane);
    }

    // out[b][rank][c_in_batch]
    if (lane < KNN) {
        out[((size_t)b * KNN + lane) * KK + (cc & 1023)] = (int)res;
    }
}

extern "C" void kernel_launch(void* const* d_in, const int* in_sizes, int n_in,
                              void* d_out, int out_size, void* d_ws, size_t ws_size,
                              hipStream_t stream) {
    const float* xyz = (const float*)d_in[0];
    const float* centers = (const float*)d_in[1];
    int* out = (int*)d_out;
    (void)d_ws; (void)ws_size;

    const int nblocks = BB * KK / 4;   // 2048 blocks x 4 waves = 8 blocks/CU, one shot
    hipLaunchKernelGGL(knn_kernel, dim3(nblocks), dim3(256), 0, stream,
                       xyz, centers, out);
}